// Round 8
// baseline (219.840 us; speedup 1.0000x reference)
//
#include <hip/hip_runtime.h>
#include <cmath>

#define HID 128
#define TM 64           // tile rows per block
#define MAXK 8          // max tiles a segment can span (seg len <= ~512)
#define PIECE_F 132     // floats per piece: [m, d, pad, pad, p[128]]
#define XPITCH 272      // shorts per LDS row: 16 chunks x (8 hi + 8 lo) + pad

typedef __attribute__((ext_vector_type(8))) short bf16x8;
typedef __attribute__((ext_vector_type(16))) float f32x16;
typedef __attribute__((ext_vector_type(4))) float f32x4;
typedef __attribute__((ext_vector_type(2))) float f32x2;
typedef __attribute__((ext_vector_type(4))) unsigned u32x4;

__device__ __forceinline__ unsigned rne_bf16_bits(float f) {
    unsigned u = __builtin_bit_cast(unsigned, f);
    return (u + 0x7FFFu + ((u >> 16) & 1u)) & 0xFFFF0000u;
}

__device__ __forceinline__ float fast_tanh(float x) {
    float e = __expf(2.0f * x);
    return 1.0f - 2.0f * __builtin_amdgcn_rcpf(e + 1.0f);
}

// Truncation split of 8 floats into bf16 hi + lo (hi+lo == f to ~2^-16 rel).
__device__ __forceinline__ void split8(const float* f, bf16x8& hi, bf16x8& lo) {
    u32x4 h, l;
    #pragma unroll
    for (int p = 0; p < 4; ++p) {
        unsigned u0 = __builtin_bit_cast(unsigned, f[2 * p]);
        unsigned u1 = __builtin_bit_cast(unsigned, f[2 * p + 1]);
        h[p] = (u0 >> 16) | (u1 & 0xFFFF0000u);
        float hf0 = __builtin_bit_cast(float, u0 & 0xFFFF0000u);
        float hf1 = __builtin_bit_cast(float, u1 & 0xFFFF0000u);
        unsigned d0 = __builtin_bit_cast(unsigned, f[2 * p] - hf0);
        unsigned d1 = __builtin_bit_cast(unsigned, f[2 * p + 1] - hf1);
        l[p] = (d0 >> 16) | (d1 & 0xFFFF0000u);
    }
    hi = __builtin_bit_cast(bf16x8, h);
    lo = __builtin_bit_cast(bf16x8, l);
}

// ---------------------------------------------------------------------------
// Prep: W -> bf16 RNE in per-wave register-fragment order for 32x32x16:
// id = (wv*8 + kc)*64 + lane holds W[wv*32 + (lane&31)][kc*16 + (lane>>5)*8 + q]
// ---------------------------------------------------------------------------
__global__ __launch_bounds__(256) void prep_w_frag(
    const float* __restrict__ W, short* __restrict__ whi)
{
    int id = blockIdx.x * 256 + threadIdx.x;    // 0..2047
    int l  = id & 63;
    int kc = (id >> 6) & 7;
    int wv = id >> 9;                           // 0..3
    int j  = wv * 32 + (l & 31);
    int k0 = kc * 16 + ((l >> 5) << 3);
    const float* src = W + j * HID + k0;
    short h8[8];
    #pragma unroll
    for (int q = 0; q < 8; ++q)
        h8[q] = (short)(rne_bf16_bits(src[q]) >> 16);
    *(bf16x8*)(whi + (size_t)id * 8) = *(const bf16x8*)h8;
}

// ---------------------------------------------------------------------------
// Segment starts from sorted owners (int32/int64) + first-segment per TM-tile.
// ---------------------------------------------------------------------------
__global__ void seg_start_kernel(const int* __restrict__ ow,
                                 int* __restrict__ seg_start,
                                 int* __restrict__ fseg, int N, int S)
{
    const int is64 = (ow[(size_t)N - 1] == 0) ? 1 : 0;
    long i = (long)blockIdx.x * blockDim.x + threadIdx.x;
    if (i > N) return;
    int a = (i == 0) ? -1 : ow[is64 ? (size_t)(2 * (i - 1)) : (size_t)(i - 1)];
    int b = (i == N) ? S  : ow[is64 ? (size_t)(2 * i)       : (size_t)i];
    for (int s = a + 1; s <= b; ++s) seg_start[s] = (int)i;
    if (i < N && (i & (TM - 1)) == 0) fseg[i >> 6] = b;  // owner of row i
}

// ---------------------------------------------------------------------------
// Fused, 64-row tile. Wave owns 32 output cols (j); W slice lives in 32 VGPRs.
// X pre-split to bf16 hi/lo at staging; LDS row pitch 544 B (2-way = free).
// Phase 2 reads X from global (L2-hot) + u from 4-way u_part.
// ---------------------------------------------------------------------------
__global__ __launch_bounds__(256, 4) void fused_kernel(
    const float* __restrict__ X, const short* __restrict__ whi_g,
    const float* __restrict__ bproj, const float* __restrict__ wscore,
    const int* __restrict__ seg_start, const int* __restrict__ fseg,
    float* __restrict__ pieces, int N, int S)
{
    __shared__ __align__(16) short X_lds[TM * XPITCH];  // 34 KB
    __shared__ float u_part[4][TM];
    __shared__ float w_lds[TM];
    __shared__ float bw_lds[2 * HID];

    const int tid  = threadIdx.x;
    const int bIdx = blockIdx.x;
    const int rbase = bIdx * TM;
    const int limit = (N - rbase < TM) ? (N - rbase) : TM;

    const int lane = tid & 63;
    const int wv   = tid >> 6;
    const int l31  = lane & 31;
    const int hig  = lane >> 5;

    // --- W slice for this wave: 8 frags = 32 VGPRs, loaded once ---
    bf16x8 wf[8];
    #pragma unroll
    for (int kc = 0; kc < 8; ++kc)
        wf[kc] = *(const bf16x8*)(whi_g + (size_t)((wv * 8 + kc) * 64 + lane) * 8);

    const int sseg0 = fseg[bIdx];
    int svl = sseg0 + lane;
    int sv  = seg_start[(svl <= S) ? svl : S];

    // --- stage X: read 32B/thread, split once, write hi/lo chunks ---
    #pragma unroll
    for (int it = 0; it < 4; ++it) {
        int id = it * 256 + tid;          // 0..1023 chunk index
        int r  = id >> 4;                 // 0..63
        int c  = id & 15;                 // 8-float chunk
        int grow = rbase + r;
        if (grow >= N) grow = N - 1;
        float a8[8];
        *(f32x4*)(a8)     = *(const f32x4*)(X + (size_t)grow * HID + c * 8);
        *(f32x4*)(a8 + 4) = *(const f32x4*)(X + (size_t)grow * HID + c * 8 + 4);
        bf16x8 hi, lo;
        split8(a8, hi, lo);
        int off = r * XPITCH + c * 16;
        *(bf16x8*)(&X_lds[off])     = hi;
        *(bf16x8*)(&X_lds[off + 8]) = lo;
    }
    if (tid < HID) {
        bw_lds[tid]       = bproj[tid];
        bw_lds[HID + tid] = wscore[tid];
    }
    __syncthreads();

    // ---- MFMA: v[j][i]; wave covers j in [wv*32, wv*32+32), i in [0,64) ----
    f32x16 acc0, acc1;
    #pragma unroll
    for (int g = 0; g < 16; ++g) { acc0[g] = 0.0f; acc1[g] = 0.0f; }

    #pragma unroll
    for (int kc = 0; kc < 8; ++kc) {
        int c = kc * 2 + hig;             // chunk holding this lane's k-octet
        int a0 = l31 * XPITCH + c * 16;
        bf16x8 xh0 = *(const bf16x8*)(&X_lds[a0]);
        bf16x8 xl0 = *(const bf16x8*)(&X_lds[a0 + 8]);
        acc0 = __builtin_amdgcn_mfma_f32_32x32x16_bf16(wf[kc], xh0, acc0, 0, 0, 0);
        acc0 = __builtin_amdgcn_mfma_f32_32x32x16_bf16(wf[kc], xl0, acc0, 0, 0, 0);
        int a1 = (32 + l31) * XPITCH + c * 16;
        bf16x8 xh1 = *(const bf16x8*)(&X_lds[a1]);
        bf16x8 xl1 = *(const bf16x8*)(&X_lds[a1 + 8]);
        acc1 = __builtin_amdgcn_mfma_f32_32x32x16_bf16(wf[kc], xh1, acc1, 0, 0, 0);
        acc1 = __builtin_amdgcn_mfma_f32_32x32x16_bf16(wf[kc], xl1, acc1, 0, 0, 0);
    }

    // ---- epilogue: partial u over this wave's 32 j's ----
    // D layout (32x32): col i = lane&31; row j = (reg&3)+8*(reg>>2)+4*hig
    float s0 = 0.0f, s1 = 0.0f;
    #pragma unroll
    for (int reg = 0; reg < 16; ++reg) {
        int j = wv * 32 + (reg & 3) + ((reg >> 2) << 3) + (hig << 2);
        float wj = bw_lds[HID + j], bj = bw_lds[j];
        s0 = fmaf(fast_tanh(acc0[reg] + bj), wj, s0);
        s1 = fmaf(fast_tanh(acc1[reg] + bj), wj, s1);
    }
    s0 += __shfl_xor(s0, 32, 64);
    s1 += __shfl_xor(s1, 32, 64);
    if (hig == 0) {
        u_part[wv][l31]      = s0;
        u_part[wv][32 + l31] = s1;
    }
    __syncthreads();

    // ---- phase 2: one wave per piece; X from global (L2-hot) ----
    for (int i = wv; ; i += 4) {
        int st, en;
        if (i < 63) {
            st = __shfl(sv, i, 64);
            en = __shfl(sv, i + 1, 64);
        } else {
            int s0i = sseg0 + i;
            st = seg_start[(s0i     <= S) ? s0i     : S];
            en = seg_start[(s0i + 1 <= S) ? s0i + 1 : S];
        }
        if (st >= rbase + limit) break;    // starts monotone -> done
        if (en <= st) continue;            // empty segment
        int a  = st - rbase; if (a < 0) a = 0;
        int bb = en - rbase; if (bb > limit) bb = limit;
        if (a >= bb) continue;

        float uv = -INFINITY;
        if (a + lane < bb)
            uv = u_part[0][a + lane] + u_part[1][a + lane]
               + u_part[2][a + lane] + u_part[3][a + lane];
        float m = uv;
        #pragma unroll
        for (int o = 32; o > 0; o >>= 1) m = fmaxf(m, __shfl_xor(m, o, 64));
        float e0 = (a + lane < bb) ? __expf(uv - m) : 0.0f;
        float d = e0;
        #pragma unroll
        for (int o = 32; o > 0; o >>= 1) d += __shfl_xor(d, o, 64);
        if (a + lane < bb) w_lds[a + lane] = e0;

        // p[c] = sum_r e_r * x[r][c]; lane owns cols {2*lane, 2*lane+1}
        f32x2 p = {0.0f, 0.0f};
        for (int rr = a; rr < bb; rr += 4) {
            #pragma unroll
            for (int q = 0; q < 4; ++q) {
                int rq = rr + q;
                int rc = (rq < bb) ? rq : (bb - 1);
                float wq = w_lds[rc];
                wq = (rq < bb) ? wq : 0.0f;
                f32x2 xv = *(const f32x2*)(
                    X + (size_t)(rbase + rc) * HID + 2 * lane);
                p.x = fmaf(wq, xv.x, p.x);
                p.y = fmaf(wq, xv.y, p.y);
            }
        }

        int sseg = sseg0 + i;
        int slot = (bIdx - (st >> 6)) & (MAXK - 1);
        float* dst = pieces + ((size_t)sseg * MAXK + slot) * PIECE_F;
        if (lane == 0) { dst[0] = m; dst[1] = d; }
        *(f32x2*)(dst + 4 + 2 * lane) = p;
    }
}

// ---------------------------------------------------------------------------
// Fixup: merge pieces per segment -> z[s][:].
// ---------------------------------------------------------------------------
__global__ __launch_bounds__(64) void fixup_kernel(
    const float* __restrict__ pieces, const int* __restrict__ seg_start,
    float* __restrict__ z)
{
    const int s = blockIdx.x;
    const int lane = threadIdx.x;
    const int start = seg_start[s];
    const int end   = seg_start[s + 1];

    if (start >= end) {
        f32x2 zo = {0.0f, 0.0f};
        *(f32x2*)(z + (size_t)s * HID + lane * 2) = zo;
        return;
    }
    int K = ((end - 1) >> 6) - (start >> 6) + 1;
    if (K > MAXK) K = MAXK;

    const float* base0 = pieces + (size_t)s * MAXK * PIECE_F;
    float M = -INFINITY;
    for (int k = 0; k < K; ++k) M = fmaxf(M, base0[k * PIECE_F]);

    float D = 0.0f;
    f32x2 zz = {0.0f, 0.0f};
    for (int k = 0; k < K; ++k) {
        const float* b = base0 + k * PIECE_F;
        float sc = __expf(b[0] - M);
        D = fmaf(b[1], sc, D);
        f32x2 pv = *(const f32x2*)(b + 4 + lane * 2);
        zz.x = fmaf(sc, pv.x, zz.x);
        zz.y = fmaf(sc, pv.y, zz.y);
    }
    float inv = 1.0f / D;
    f32x2 zo = {zz.x * inv, zz.y * inv};
    *(f32x2*)(z + (size_t)s * HID + lane * 2) = zo;
}

// ---------------------------------------------------------------------------
extern "C" void kernel_launch(void* const* d_in, const int* in_sizes, int n_in,
                              void* d_out, int out_size, void* d_ws, size_t ws_size,
                              hipStream_t stream)
{
    const float* X   = (const float*)d_in[0];
    const int*   ow  = (const int*)  d_in[1];
    const float* W   = (const float*)d_in[2];
    const float* bp  = (const float*)d_in[3];
    const float* wsc = (const float*)d_in[4];

    const int N  = in_sizes[0] / HID;
    const int S  = out_size / HID;
    const int NT = (N + TM - 1) / TM;

    char* ws = (char*)d_ws;
    size_t off_seg = 0;
    size_t off_fs  = (((size_t)(S + 1) * 4) + 255) & ~(size_t)255;
    size_t off_w   = (off_fs + (size_t)NT * 4 + 255) & ~(size_t)255;
    size_t off_pc  = (off_w + (size_t)HID * HID * 2 + 255) & ~(size_t)255;

    int*   seg    = (int*)  (ws + off_seg);
    int*   fsg    = (int*)  (ws + off_fs);
    short* whi    = (short*)(ws + off_w);
    float* pieces = (float*)(ws + off_pc);
    float* z      = (float*)d_out;

    const int blocksB = ((N + 1) + 255) / 256;
    seg_start_kernel<<<blocksB, 256, 0, stream>>>(ow, seg, fsg, N, S);

    prep_w_frag<<<8, 256, 0, stream>>>(W, whi);

    fused_kernel<<<NT, 256, 0, stream>>>(X, whi, bp, wsc, seg, fsg,
                                         pieces, N, S);

    fixup_kernel<<<S, 64, 0, stream>>>(pieces, seg, z);
}